// Round 4
// baseline (2241.373 us; speedup 1.0000x reference)
//
#include <hip/hip_runtime.h>
#include <hip/hip_fp16.h>

#define N_NODES 100000
#define N_EDGES 1200000
#define TOTAL_E (2 * N_EDGES)
#define D 64

#define BSH 7                       // bucket = node >> 7 (128 nodes/bucket)
#define NBUCK 782                   // ceil(100000/128)
#define NCHUNK 320
#define CHUNK 7500                  // NCHUNK * CHUNK == TOTAL_E
#define HIST_L (NBUCK * NCHUNK)     // 250240 (per side; hist array holds 2x)
#define SCAN_BS 256
#define SCAN_NB ((HIST_L + SCAN_BS - 1) / SCAN_BS)  // 978
#define ENT_CAP 4608                // bucket mean 3072, sigma 55 -> +28 sigma
#define L2M_GRID ((N_NODES + 127) / 128)  // 782
#define NKEYS 3584                  // sortB keys: (src>>13:0..12)<<8 | rel<<7 | dl; padded to 512*7

typedef __attribute__((ext_vector_type(8))) short bf16x8;
typedef __attribute__((ext_vector_type(4))) float f32x4;

__device__ __forceinline__ unsigned short f32_bf16_rne(float f) {
    unsigned u = __float_as_uint(f);
    unsigned r = u + 0x7FFF + ((u >> 16) & 1);
    return (unsigned short)(r >> 16);
}
__device__ __forceinline__ float bf16_f32(unsigned short h) {
    return __uint_as_float(((unsigned)h) << 16);
}

// ---------------------------------------------------------------------------
// Per-chunk LDS histograms of dst buckets AND src buckets. No global atomics.
// hist layout: [0, HIST_L) = dst-side, [HIST_L, 2*HIST_L) = src-side.
// ---------------------------------------------------------------------------
__global__ __launch_bounds__(512) void countA_kernel(const int* __restrict__ s0,
                                                     const int* __restrict__ d0,
                                                     const int* __restrict__ s1,
                                                     const int* __restrict__ d1,
                                                     int* __restrict__ hist) {
    __shared__ int hD[NBUCK];
    __shared__ int hS[NBUCK];
    int t = threadIdx.x;
    for (int i = t; i < NBUCK; i += 512) { hD[i] = 0; hS[i] = 0; }
    __syncthreads();
    int base = blockIdx.x * CHUNK;
    for (int i = t; i < CHUNK; i += 512) {
        int e = base + i;
        int rel = (e >= N_EDGES);
        int src = rel ? s1[e - N_EDGES] : s0[e];
        int dst = rel ? d1[e - N_EDGES] : d0[e];
        atomicAdd(&hD[dst >> BSH], 1);
        atomicAdd(&hS[src >> BSH], 1);
    }
    __syncthreads();
    for (int i = t; i < NBUCK; i += 512) {
        hist[i * NCHUNK + blockIdx.x] = hD[i];
        hist[HIST_L + i * NCHUNK + blockIdx.x] = hS[i];
    }
}

// ---------------------------------------------------------------------------
// Exclusive scan over HIST_L ints (invoked twice: dst half, src half).
// ---------------------------------------------------------------------------
__global__ void scan1_kernel(const int* __restrict__ in, int* __restrict__ out,
                             int* __restrict__ bsum) {
    __shared__ int s[SCAN_BS];
    int t = threadIdx.x;
    int i = blockIdx.x * SCAN_BS + t;
    int v = (i < HIST_L) ? in[i] : 0;
    s[t] = v;
    __syncthreads();
    for (int off = 1; off < SCAN_BS; off <<= 1) {
        int add = (t >= off) ? s[t - off] : 0;
        __syncthreads();
        s[t] += add;
        __syncthreads();
    }
    if (i < HIST_L) out[i] = s[t] - v;
    if (t == SCAN_BS - 1) bsum[blockIdx.x] = s[t];
}

__global__ void scan2_kernel(int* __restrict__ bsum) {
    __shared__ int s[1024];
    int t = threadIdx.x;
    int v = (t < SCAN_NB) ? bsum[t] : 0;
    s[t] = v;
    __syncthreads();
    for (int off = 1; off < 1024; off <<= 1) {
        int add = (t >= off) ? s[t - off] : 0;
        __syncthreads();
        s[t] += add;
        __syncthreads();
    }
    if (t < SCAN_NB) bsum[t] = s[t] - v;
}

__global__ void scan3_kernel(int* __restrict__ out, const int* __restrict__ bsum) {
    int i = blockIdx.x * SCAN_BS + threadIdx.x;
    if (i < HIST_L) out[i] += bsum[blockIdx.x];
    if (i == 0) out[HIST_L] = TOTAL_E;
}

// ---------------------------------------------------------------------------
// Scatter packed entries into bucket-binned arrays.
// dst entry (u32) = src | dl<<17 | rel<<24  -> binned
// src entry (u8)  = sl | rel<<7             -> binnedS (for out-degree counts)
// ---------------------------------------------------------------------------
__global__ __launch_bounds__(512) void scatterA_kernel(const int* __restrict__ s0,
                                                       const int* __restrict__ d0,
                                                       const int* __restrict__ s1,
                                                       const int* __restrict__ d1,
                                                       const int* __restrict__ ofs,
                                                       const int* __restrict__ ofsS,
                                                       unsigned* __restrict__ binned,
                                                       unsigned char* __restrict__ binnedS) {
    __shared__ int cur[NBUCK];
    __shared__ int curS[NBUCK];
    int t = threadIdx.x, wg = blockIdx.x;
    for (int b = t; b < NBUCK; b += 512) {
        cur[b] = ofs[b * NCHUNK + wg];
        curS[b] = ofsS[b * NCHUNK + wg];
    }
    __syncthreads();
    int base = wg * CHUNK;
    for (int i = t; i < CHUNK; i += 512) {
        int e = base + i;
        int rel = (e >= N_EDGES);
        int src = rel ? s1[e - N_EDGES] : s0[e];
        int dst = rel ? d1[e - N_EDGES] : d0[e];
        int p = atomicAdd(&cur[dst >> BSH], 1);
        binned[p] = (unsigned)src | ((unsigned)(dst & 127) << 17) | ((unsigned)rel << 24);
        int q = atomicAdd(&curS[src >> BSH], 1);
        binnedS[q] = (unsigned char)((src & 127) | (rel << 7));
    }
}

// ---------------------------------------------------------------------------
// Per-bucket LDS counting sort (in place), key = (src>>13)<<8 | rel<<7 | dl.
// Entries stay FULL (src|dl|rel) — aggD decodes them. Ordering is src-slice-
// major so ALL co-resident aggD blocks sweep the same 1 MB gather-table slice
// simultaneously (device-synchronized sweep -> L2-resident band).
// Per-(node,rel) in-degree counts come from the histogram.
// ---------------------------------------------------------------------------
__global__ __launch_bounds__(512) void sortB_kernel(unsigned* __restrict__ binned,
                                                    const int* __restrict__ ofs,
                                                    unsigned short* __restrict__ c0a,
                                                    unsigned short* __restrict__ c1a) {
    __shared__ unsigned ent[ENT_CAP];
    __shared__ int cnt[NKEYS], cur[NKEYS];
    __shared__ int tsum[512];
    int t = threadIdx.x;
    int b = blockIdx.x;
    int start = ofs[b * NCHUNK];
    int end = ofs[(b + 1) * NCHUNK];
    int n = end - start;

    for (int i = t; i < NKEYS; i += 512) cnt[i] = 0;
    __syncthreads();
    for (int i = t; i < n; i += 512) {
        unsigned u = binned[start + i];
        if (i < ENT_CAP) ent[i] = u;
        int key = (int)((u & 0x1FFFFu) >> 13) * 256 + (int)((u >> 17) & 255);
        atomicAdd(&cnt[key], 1);
    }
    __syncthreads();
    // Exclusive scan over NKEYS: 7 keys/thread serial + 512-wide Hillis-Steele.
    int c7[7];
    int run = 0;
    int base7 = t * 7;
#pragma unroll
    for (int j = 0; j < 7; ++j) { c7[j] = run; run += cnt[base7 + j]; }
    tsum[t] = run;
    __syncthreads();
    for (int off = 1; off < 512; off <<= 1) {
        int add = (t >= off) ? tsum[t - off] : 0;
        __syncthreads();
        tsum[t] += add;
        __syncthreads();
    }
    int ex = tsum[t] - run;
#pragma unroll
    for (int j = 0; j < 7; ++j) cur[base7 + j] = ex + c7[j];
    __syncthreads();
    for (int i = t; i < n; i += 512) {
        if (i < ENT_CAP) {
            unsigned u = ent[i];
            int key = (int)((u & 0x1FFFFu) >> 13) * 256 + (int)((u >> 17) & 255);
            int p = atomicAdd(&cur[key], 1);
            binned[start + p] = u;   // keep full entry
        }
    }
    if (t < 128) {
        int node = b * 128 + t;
        if (node < N_NODES) {
            int sA = 0, sB = 0;
#pragma unroll
            for (int sp = 0; sp < 13; ++sp) {
                sA += cnt[sp * 256 + t];
                sB += cnt[sp * 256 + 128 + t];
            }
            c0a[node] = (unsigned short)sA;
            c1a[node] = (unsigned short)sB;
        }
    }
}

// ---------------------------------------------------------------------------
// Per-src-bucket out-degree counts from the byte-binned entries.
// ---------------------------------------------------------------------------
__global__ __launch_bounds__(512) void countO_kernel(const unsigned char* __restrict__ binnedS,
                                                     const int* __restrict__ ofsS,
                                                     int* __restrict__ cntO0,
                                                     int* __restrict__ cntO1) {
    __shared__ int cnt[256];
    int t = threadIdx.x;
    int b = blockIdx.x;
    int start = ofsS[b * NCHUNK];
    int end = ofsS[(b + 1) * NCHUNK];
    if (t < 256) cnt[t] = 0;
    __syncthreads();
    for (int i = start + t; i < end; i += 512)
        atomicAdd(&cnt[(int)binnedS[i]], 1);
    __syncthreads();
    if (t < 128) {
        int node = b * 128 + t;
        if (node < N_NODES) {
            cntO0[node] = cnt[t];
            cntO1[node] = cnt[t | 128];
        }
    }
}

// ---------------------------------------------------------------------------
// Pre-split W into bf16 hi/lo MFMA B-fragments, per-lane contiguous order.
// ---------------------------------------------------------------------------
__global__ void wprep_kernel(const float* __restrict__ W0,
                             const float* __restrict__ W1,
                             short* __restrict__ Wf) {
    int t = blockIdx.x * blockDim.x + threadIdx.x;
    if (t >= 2 * 4096) return;
    int rel = t >> 12;
    int e = t & 4095;
    int k = e >> 6, col = e & 63;
    float wv = (rel ? W1 : W0)[e];
    unsigned short hi = f32_bf16_rne(wv);
    unsigned short lo = f32_bf16_rne(wv - bf16_f32(hi));
    int kstep = k >> 5, g = (k >> 3) & 3, j = k & 7;
    int base = ((((rel * 2 + 0) * 2 + kstep) * 4 + g) * 64 + col) * 8 + j;
    int baseL = ((((rel * 2 + 1) * 2 + kstep) * 4 + g) * 64 + col) * 8 + j;
    Wf[base] = (short)hi;
    Wf[baseL] = (short)lo;
}

// ---------------------------------------------------------------------------
// MFMA linears: Y0 = (X@W0)*rsqrt(degO0), Y1 = (X@W1)*rsqrt(degO1), fp16 out.
// Split-bf16 (hi+lo, 3 MFMAs). 128 rows/block, 4 waves, 2 m-tiles/wave.
// ---------------------------------------------------------------------------
__global__ __launch_bounds__(256) void lin2m_kernel(const float* __restrict__ x,
                                                    const short* __restrict__ Wf,
                                                    const int* __restrict__ cntO0,
                                                    const int* __restrict__ cntO1,
                                                    __half* __restrict__ y0,
                                                    __half* __restrict__ y1) {
    int t = threadIdx.x;
    int w = t >> 6, lane = t & 63;
    int lr = lane & 15, g = lane >> 4;
    int rowbase = blockIdx.x * 128 + w * 32;

    bf16x8 ah[2][2], al[2][2];
#pragma unroll
    for (int m = 0; m < 2; ++m) {
        int row = rowbase + m * 16 + lr;
        bool ok = row < N_NODES;
        const float* xp = x + (size_t)row * 64 + g * 8;
#pragma unroll
        for (int s = 0; s < 2; ++s) {
            float fv[8];
            if (ok) {
                float4 f0 = ((const float4*)(xp + s * 32))[0];
                float4 f1 = ((const float4*)(xp + s * 32))[1];
                fv[0] = f0.x; fv[1] = f0.y; fv[2] = f0.z; fv[3] = f0.w;
                fv[4] = f1.x; fv[5] = f1.y; fv[6] = f1.z; fv[7] = f1.w;
            } else {
#pragma unroll
                for (int j = 0; j < 8; ++j) fv[j] = 0.f;
            }
#pragma unroll
            for (int j = 0; j < 8; ++j) {
                unsigned short hi = f32_bf16_rne(fv[j]);
                unsigned short lo = f32_bf16_rne(fv[j] - bf16_f32(hi));
                ah[m][s][j] = (short)hi;
                al[m][s][j] = (short)lo;
            }
        }
    }

    float rsc[2][2][4];
#pragma unroll
    for (int m = 0; m < 2; ++m)
#pragma unroll
        for (int reg = 0; reg < 4; ++reg) {
            int row = rowbase + m * 16 + g * 4 + reg;
            bool ok = row < N_NODES;
            rsc[0][m][reg] = ok ? rsqrtf((float)max(cntO0[row], 1)) : 1.f;
            rsc[1][m][reg] = ok ? rsqrtf((float)max(cntO1[row], 1)) : 1.f;
        }

#pragma unroll
    for (int rel = 0; rel < 2; ++rel) {
        __half* yo = rel ? y1 : y0;
        const short* wr = Wf + rel * 8192 + g * 512;
#pragma unroll
        for (int n = 0; n < 4; ++n) {
            const short* wb = wr + (n * 16 + lr) * 8;
            bf16x8 wh0 = *(const bf16x8*)(wb);          // hl=0, kstep=0
            bf16x8 wh1 = *(const bf16x8*)(wb + 2048);   // hl=0, kstep=1
            bf16x8 wl0 = *(const bf16x8*)(wb + 4096);   // hl=1, kstep=0
            bf16x8 wl1 = *(const bf16x8*)(wb + 6144);   // hl=1, kstep=1
#pragma unroll
            for (int m = 0; m < 2; ++m) {
                f32x4 acc = {0.f, 0.f, 0.f, 0.f};
                acc = __builtin_amdgcn_mfma_f32_16x16x32_bf16(al[m][0], wh0, acc, 0, 0, 0);
                acc = __builtin_amdgcn_mfma_f32_16x16x32_bf16(ah[m][0], wl0, acc, 0, 0, 0);
                acc = __builtin_amdgcn_mfma_f32_16x16x32_bf16(ah[m][0], wh0, acc, 0, 0, 0);
                acc = __builtin_amdgcn_mfma_f32_16x16x32_bf16(al[m][1], wh1, acc, 0, 0, 0);
                acc = __builtin_amdgcn_mfma_f32_16x16x32_bf16(ah[m][1], wl1, acc, 0, 0, 0);
                acc = __builtin_amdgcn_mfma_f32_16x16x32_bf16(ah[m][1], wh1, acc, 0, 0, 0);
#pragma unroll
                for (int reg = 0; reg < 4; ++reg) {
                    int row = rowbase + m * 16 + g * 4 + reg;
                    if (row < N_NODES)
                        yo[(size_t)row * 64 + n * 16 + lr] =
                            __float2half_rn(acc[reg] * rsc[rel][m][reg]);
                }
            }
        }
    }
}

// ---------------------------------------------------------------------------
// Output-stationary gather-aggregate: one block per dst-bucket, LDS f32
// accumulator acc[128][65] (stride 65 spreads atomic banks). 64 groups x 8
// lanes stream the src-slice-sorted entry list in order; all 782 blocks are
// co-resident (34.5 KB LDS -> 4 blocks/CU), so the device sweeps the gather
// tables in a narrow synchronized band -> L2 hits. rsqrt(deg_in) folded
// per-term; bias/ReLU in the coalesced epilogue.
// OUTH=0 -> f32 out (layer-1 h); OUTH=1 -> fp16 out (h2).
// ---------------------------------------------------------------------------
template <int RELU, int OUTH>
__global__ __launch_bounds__(512) void aggD_kernel(const __half* __restrict__ L0,
                                                   const __half* __restrict__ L1,
                                                   const unsigned* __restrict__ es,
                                                   const int* __restrict__ ofs,
                                                   const unsigned short* __restrict__ c0a,
                                                   const unsigned short* __restrict__ c1a,
                                                   const float* __restrict__ bia0,
                                                   const float* __restrict__ bia1,
                                                   float* __restrict__ outf,
                                                   __half* __restrict__ outh) {
    __shared__ float accf[128 * 65];
    __shared__ float rsc[2][128];
    __shared__ float bsum[64];
    int t = threadIdx.x;
    int b = blockIdx.x;
    int start = ofs[b * NCHUNK];
    int n = ofs[(b + 1) * NCHUNK] - start;

    for (int i = t; i < 128 * 65; i += 512) accf[i] = 0.f;
    if (t < 128) {
        int node = b * 128 + t;
        rsc[0][t] = (node < N_NODES) ? rsqrtf((float)max((int)c0a[node], 1)) : 1.f;
        rsc[1][t] = (node < N_NODES) ? rsqrtf((float)max((int)c1a[node], 1)) : 1.f;
    }
    if (t >= 128 && t < 192) bsum[t - 128] = bia0[t - 128] + bia1[t - 128];
    __syncthreads();

    int gi = t >> 3, l8 = t & 7;
    union HU { uint4 u; __half2 h[4]; };
    for (int k = gi; k < n; k += 64) {
        unsigned u = es[start + k];
        int s = (int)(u & 0x1FFFFu);
        int dl = (int)((u >> 17) & 127);
        int rel = (int)((u >> 24) & 1);
        const __half* Lp = rel ? L1 : L0;
        HU v;
        v.u = ((const uint4*)(Lp + (size_t)s * 64))[l8];
        float sc = rsc[rel][dl];
        float* ap = accf + dl * 65 + l8 * 8;
#pragma unroll
        for (int q = 0; q < 4; ++q) {
            float2 f = __half22float2(v.h[q]);
            atomicAdd(ap + 2 * q, f.x * sc);
            atomicAdd(ap + 2 * q + 1, f.y * sc);
        }
    }
    __syncthreads();

    int nd = t >> 2, q4 = t & 3;
    int node = b * 128 + nd;
    if (node >= N_NODES) return;
    float o[16];
    const float* ap = accf + nd * 65 + q4 * 16;
#pragma unroll
    for (int j = 0; j < 16; ++j) {
        o[j] = ap[j] + bsum[q4 * 16 + j];
        if (RELU) o[j] = fmaxf(o[j], 0.f);
    }
    if (OUTH) {
        union HV { uint4 u; __half2 h[4]; } va, vb;
#pragma unroll
        for (int q = 0; q < 4; ++q) va.h[q] = __floats2half2_rn(o[2 * q], o[2 * q + 1]);
#pragma unroll
        for (int q = 0; q < 4; ++q) vb.h[q] = __floats2half2_rn(o[8 + 2 * q], o[9 + 2 * q]);
        ((uint4*)(outh + (size_t)node * 64))[q4 * 2] = va.u;
        ((uint4*)(outh + (size_t)node * 64))[q4 * 2 + 1] = vb.u;
    } else {
        float4* op = (float4*)(outf + (size_t)node * 64) + q4 * 4;
        op[0] = make_float4(o[0], o[1], o[2], o[3]);
        op[1] = make_float4(o[4], o[5], o[6], o[7]);
        op[2] = make_float4(o[8], o[9], o[10], o[11]);
        op[3] = make_float4(o[12], o[13], o[14], o[15]);
    }
}

// ---------------------------------------------------------------------------
// Edge dot products on fp16 h2: 8 threads/edge, 16 B loads, f32 accumulate.
// ---------------------------------------------------------------------------
__global__ __launch_bounds__(256) void score_kernel(const __half* __restrict__ h2,
                                                    const int* __restrict__ ps,
                                                    const int* __restrict__ pd,
                                                    const int* __restrict__ ns,
                                                    const int* __restrict__ nd,
                                                    float* __restrict__ out) {
    int gid = blockIdx.x * blockDim.x + threadIdx.x;
    int e = gid >> 3;
    int l8 = gid & 7;
    if (e >= 2 * N_EDGES) return;
    int s, d;
    if (e < N_EDGES) { s = ps[e]; d = pd[e]; }
    else             { s = ns[e - N_EDGES]; d = nd[e - N_EDGES]; }
    union HU { uint4 u; __half2 h[4]; };
    HU ua, ub;
    ua.u = ((const uint4*)(h2 + (size_t)s * 64))[l8];
    ub.u = ((const uint4*)(h2 + (size_t)d * 64))[l8];
    float p = 0.f;
#pragma unroll
    for (int q = 0; q < 4; ++q) {
        float2 fa = __half22float2(ua.h[q]);
        float2 fb = __half22float2(ub.h[q]);
        p += fa.x * fb.x + fa.y * fb.y;
    }
    p += __shfl_xor(p, 1);
    p += __shfl_xor(p, 2);
    p += __shfl_xor(p, 4);
    if (l8 == 0) out[e] = p;
}

extern "C" void kernel_launch(void* const* d_in, const int* in_sizes, int n_in,
                              void* d_out, int out_size, void* d_ws, size_t ws_size,
                              hipStream_t stream) {
    const float* x    = (const float*)d_in[0];
    const int* s0     = (const int*)d_in[1];
    const int* d0     = (const int*)d_in[2];
    const int* s1     = (const int*)d_in[3];
    const int* d1     = (const int*)d_in[4];
    const int* nsrc   = (const int*)d_in[5];
    const int* ndst   = (const int*)d_in[6];
    const float* W1_0 = (const float*)d_in[7];
    const float* W1_1 = (const float*)d_in[8];
    const float* W2_0 = (const float*)d_in[9];
    const float* W2_1 = (const float*)d_in[10];
    const float* b1_0 = (const float*)d_in[11];
    const float* b1_1 = (const float*)d_in[12];
    const float* b2_0 = (const float*)d_in[13];
    const float* b2_1 = (const float*)d_in[14];
    float* out = (float*)d_out;

    // ---- workspace ----
    char* p = (char*)d_ws;
    int* cntO0 = (int*)p;      p += N_NODES * 4;
    int* cntO1 = (int*)p;      p += N_NODES * 4;
    int* hist  = (int*)p;      p += 2 * HIST_L * 4;          // dst half + src half
    int* ofs   = (int*)p;      p += (HIST_L + 1) * 4;
    int* ofsS  = (int*)p;      p += (HIST_L + 1) * 4;
    int* bsum  = (int*)p;      p += 1024 * 4;
    unsigned* binned = (unsigned*)p;  p += (size_t)TOTAL_E * 4;
    unsigned short* c0a = (unsigned short*)p;  p += N_NODES * 2;
    unsigned short* c1a = (unsigned short*)p;  p += N_NODES * 2;
    unsigned char* binnedS = (unsigned char*)p;  p += (size_t)TOTAL_E;
    p = (char*)(((size_t)p + 255) & ~(size_t)255);
    short* WfA = (short*)p;    p += 16384 * 2;               // layer-1 W frags
    short* WfB = (short*)p;    p += 16384 * 2;               // layer-2 W frags
    p = (char*)(((size_t)p + 255) & ~(size_t)255);
    __half* bufL0h = (__half*)p;  p += (size_t)N_NODES * D * 2;
    __half* bufL1h = (__half*)p;  p += (size_t)N_NODES * D * 2;
    __half* h2h    = (__half*)p;  p += (size_t)N_NODES * D * 2;
    p = (char*)(((size_t)p + 255) & ~(size_t)255);
    float* bufH = (float*)p;   p += (size_t)N_NODES * D * 4;

    const int scorGrid = (2 * N_EDGES * 8) / 256;

    // ---- W fragment prep (tiny) ----
    wprep_kernel<<<32, 256, 0, stream>>>(W1_0, W1_1, WfA);
    wprep_kernel<<<32, 256, 0, stream>>>(W2_0, W2_1, WfB);

    // ---- degrees + binning (no per-edge global atomics anywhere) ----
    countA_kernel<<<NCHUNK, 512, 0, stream>>>(s0, d0, s1, d1, hist);
    scan1_kernel<<<SCAN_NB, SCAN_BS, 0, stream>>>(hist, ofs, bsum);
    scan2_kernel<<<1, 1024, 0, stream>>>(bsum);
    scan3_kernel<<<SCAN_NB, SCAN_BS, 0, stream>>>(ofs, bsum);
    scan1_kernel<<<SCAN_NB, SCAN_BS, 0, stream>>>(hist + HIST_L, ofsS, bsum);
    scan2_kernel<<<1, 1024, 0, stream>>>(bsum);
    scan3_kernel<<<SCAN_NB, SCAN_BS, 0, stream>>>(ofsS, bsum);
    scatterA_kernel<<<NCHUNK, 512, 0, stream>>>(s0, d0, s1, d1, ofs, ofsS, binned, binnedS);
    sortB_kernel<<<NBUCK, 512, 0, stream>>>(binned, ofs, c0a, c1a);
    countO_kernel<<<NBUCK, 512, 0, stream>>>(binnedS, ofsS, cntO0, cntO1);

    // ---- layer 1 ----
    lin2m_kernel<<<L2M_GRID, 256, 0, stream>>>(x, WfA, cntO0, cntO1, bufL0h, bufL1h);
    aggD_kernel<1, 0><<<NBUCK, 512, 0, stream>>>(bufL0h, bufL1h, binned, ofs,
                                                 c0a, c1a, b1_0, b1_1, bufH, nullptr);

    // ---- layer 2 ----
    lin2m_kernel<<<L2M_GRID, 256, 0, stream>>>(bufH, WfB, cntO0, cntO1, bufL0h, bufL1h);
    aggD_kernel<0, 1><<<NBUCK, 512, 0, stream>>>(bufL0h, bufL1h, binned, ofs,
                                                 c0a, c1a, b2_0, b2_1, nullptr, h2h);

    // ---- scores ----
    score_kernel<<<scorGrid, 256, 0, stream>>>(h2h, s0, d0, nsrc, ndst, out);
}

// Round 5
// 299.859 us; speedup vs baseline: 7.4747x; 7.4747x over previous
//
#include <hip/hip_runtime.h>
#include <hip/hip_fp16.h>

#define N_NODES 100000
#define N_EDGES 1200000
#define TOTAL_E (2 * N_EDGES)
#define D 64

#define BSH 7                       // bucket = node >> 7 (128 nodes/bucket)
#define NBUCK 782                   // ceil(100000/128)
#define NCHUNK 320
#define CHUNK 7500                  // NCHUNK * CHUNK == TOTAL_E
#define HIST_L (NBUCK * NCHUNK)     // 250240 (per side)
#define HIST2 (2 * HIST_L)          // 500480 (dst half + src half, one scan)
#define SCAN_BS 256
#define SCAN_NB2 ((HIST2 + SCAN_BS - 1) / SCAN_BS)  // 1955
#define ENT_CAP 4608                // bucket mean 3072, sigma 55 -> +28 sigma
#define L2M_GRID ((N_NODES + 127) / 128)  // 782
#define NKEY 2048                   // sortB key: rel(1) | dl(7) | src_super(3)

typedef __attribute__((ext_vector_type(8))) short bf16x8;
typedef __attribute__((ext_vector_type(4))) float f32x4;

__device__ __forceinline__ unsigned short f32_bf16_rne(float f) {
    unsigned u = __float_as_uint(f);
    unsigned r = u + 0x7FFF + ((u >> 16) & 1);
    return (unsigned short)(r >> 16);
}
__device__ __forceinline__ float bf16_f32(unsigned short h) {
    return __uint_as_float(((unsigned)h) << 16);
}

// ---------------------------------------------------------------------------
// Per-chunk LDS histograms of dst buckets AND src buckets. No global atomics.
// hist layout: [0, HIST_L) = dst-side, [HIST_L, HIST2) = src-side.
// ---------------------------------------------------------------------------
__global__ __launch_bounds__(512) void countA_kernel(const int* __restrict__ s0,
                                                     const int* __restrict__ d0,
                                                     const int* __restrict__ s1,
                                                     const int* __restrict__ d1,
                                                     int* __restrict__ hist) {
    __shared__ int hD[NBUCK];
    __shared__ int hS[NBUCK];
    int t = threadIdx.x;
    for (int i = t; i < NBUCK; i += 512) { hD[i] = 0; hS[i] = 0; }
    __syncthreads();
    int base = blockIdx.x * CHUNK;
    for (int i = t; i < CHUNK; i += 512) {
        int e = base + i;
        int rel = (e >= N_EDGES);
        int src = rel ? s1[e - N_EDGES] : s0[e];
        int dst = rel ? d1[e - N_EDGES] : d0[e];
        atomicAdd(&hD[dst >> BSH], 1);
        atomicAdd(&hS[src >> BSH], 1);
    }
    __syncthreads();
    for (int i = t; i < NBUCK; i += 512) {
        hist[i * NCHUNK + blockIdx.x] = hD[i];
        hist[HIST_L + i * NCHUNK + blockIdx.x] = hS[i];
    }
}

// ---------------------------------------------------------------------------
// ONE exclusive scan over HIST2 ints (dst+src halves contiguous).
// Src-side offsets are OFS[HIST_L + i] - TOTAL_E.
// ---------------------------------------------------------------------------
__global__ void scan1_kernel(const int* __restrict__ in, int* __restrict__ out,
                             int* __restrict__ bsum) {
    __shared__ int s[SCAN_BS];
    int t = threadIdx.x;
    int i = blockIdx.x * SCAN_BS + t;
    int v = (i < HIST2) ? in[i] : 0;
    s[t] = v;
    __syncthreads();
    for (int off = 1; off < SCAN_BS; off <<= 1) {
        int add = (t >= off) ? s[t - off] : 0;
        __syncthreads();
        s[t] += add;
        __syncthreads();
    }
    if (i < HIST2) out[i] = s[t] - v;
    if (t == SCAN_BS - 1) bsum[blockIdx.x] = s[t];
}

__global__ void scan2_kernel(int* __restrict__ bsum) {
    __shared__ int s[1024];
    int t = threadIdx.x;
    int v0 = (2 * t < SCAN_NB2) ? bsum[2 * t] : 0;
    int v1 = (2 * t + 1 < SCAN_NB2) ? bsum[2 * t + 1] : 0;
    int sum = v0 + v1;
    s[t] = sum;
    __syncthreads();
    for (int off = 1; off < 1024; off <<= 1) {
        int add = (t >= off) ? s[t - off] : 0;
        __syncthreads();
        s[t] += add;
        __syncthreads();
    }
    int ex = s[t] - sum;
    if (2 * t < SCAN_NB2) bsum[2 * t] = ex;
    if (2 * t + 1 < SCAN_NB2) bsum[2 * t + 1] = ex + v0;
}

__global__ void scan3_kernel(int* __restrict__ out, const int* __restrict__ bsum) {
    int i = blockIdx.x * SCAN_BS + threadIdx.x;
    if (i < HIST2) out[i] += bsum[blockIdx.x];
    if (i == 0) out[HIST2] = 2 * TOTAL_E;
}

// ---------------------------------------------------------------------------
// Scatter packed entries into bucket-binned arrays.
// dst entry (u32) = src | dl<<17 | rel<<24  -> binned
// src entry (u8)  = sl | rel<<7             -> binnedS (out-degree counts)
// ---------------------------------------------------------------------------
__global__ __launch_bounds__(512) void scatterA_kernel(const int* __restrict__ s0,
                                                       const int* __restrict__ d0,
                                                       const int* __restrict__ s1,
                                                       const int* __restrict__ d1,
                                                       const int* __restrict__ OFS,
                                                       unsigned* __restrict__ binned,
                                                       unsigned char* __restrict__ binnedS) {
    __shared__ int cur[NBUCK];
    __shared__ int curS[NBUCK];
    int t = threadIdx.x, wg = blockIdx.x;
    for (int b = t; b < NBUCK; b += 512) {
        cur[b] = OFS[b * NCHUNK + wg];
        curS[b] = OFS[HIST_L + b * NCHUNK + wg] - TOTAL_E;
    }
    __syncthreads();
    int base = wg * CHUNK;
    for (int i = t; i < CHUNK; i += 512) {
        int e = base + i;
        int rel = (e >= N_EDGES);
        int src = rel ? s1[e - N_EDGES] : s0[e];
        int dst = rel ? d1[e - N_EDGES] : d0[e];
        int p = atomicAdd(&cur[dst >> BSH], 1);
        binned[p] = (unsigned)src | ((unsigned)(dst & 127) << 17) | ((unsigned)rel << 24);
        int q = atomicAdd(&curS[src >> BSH], 1);
        binnedS[q] = (unsigned char)((src & 127) | (rel << 7));
    }
}

// ---------------------------------------------------------------------------
// Per-bucket LDS counting sort (in place): binned -> src indices grouped by
// key = rel<<10 | dl<<3 | src_super (src_super = src>>14, 0..6).
// ---------------------------------------------------------------------------
__global__ __launch_bounds__(512) void sortB_kernel(unsigned* __restrict__ binned,
                                                    const int* __restrict__ OFS,
                                                    int* __restrict__ ip0,
                                                    int* __restrict__ ip1,
                                                    unsigned short* __restrict__ c0a,
                                                    unsigned short* __restrict__ c1a) {
    __shared__ unsigned ent[ENT_CAP];
    __shared__ int cnt[NKEY], pfx[NKEY], cur[NKEY];
    __shared__ int tsum[512];
    int t = threadIdx.x;
    int b = blockIdx.x;
    int start = OFS[b * NCHUNK];
    int end = OFS[(b + 1) * NCHUNK];
    int n = end - start;

    for (int i = t; i < NKEY; i += 512) cnt[i] = 0;
    __syncthreads();
    for (int i = t; i < n; i += 512) {
        unsigned u = binned[start + i];
        if (i < ENT_CAP) ent[i] = u;
        int key = ((int)((u >> 17) & 255) << 3) | (int)((u & 0x1FFFFu) >> 14);
        atomicAdd(&cnt[key], 1);
    }
    __syncthreads();
    int b4 = t * 4;
    int k0 = cnt[b4], k1 = cnt[b4 + 1], k2 = cnt[b4 + 2], k3 = cnt[b4 + 3];
    int s1 = k0 + k1, s2 = s1 + k2, s3 = s2 + k3;
    tsum[t] = s3;
    __syncthreads();
    for (int off = 1; off < 512; off <<= 1) {
        int add = (t >= off) ? tsum[t - off] : 0;
        __syncthreads();
        tsum[t] += add;
        __syncthreads();
    }
    int ex = tsum[t] - s3;
    pfx[b4] = ex;
    pfx[b4 + 1] = ex + k0;
    pfx[b4 + 2] = ex + s1;
    pfx[b4 + 3] = ex + s2;
    cur[b4] = ex;
    cur[b4 + 1] = ex + k0;
    cur[b4 + 2] = ex + s1;
    cur[b4 + 3] = ex + s2;
    __syncthreads();
    for (int i = t; i < n; i += 512) {
        if (i < ENT_CAP) {
            unsigned u = ent[i];
            int key = ((int)((u >> 17) & 255) << 3) | (int)((u & 0x1FFFFu) >> 14);
            int p = atomicAdd(&cur[key], 1);
            binned[start + p] = u & 0x1FFFF;
        }
    }
    if (t < 128) {
        int node = b * 128 + t;
        if (node < N_NODES) {
            int kr0 = t << 3;
            int kr1 = (1 << 10) | (t << 3);
            int p0 = pfx[kr0];
            int e0 = pfx[kr0 + 8];
            int p1 = pfx[kr1];
            int e1 = (t == 127) ? n : pfx[kr1 + 8];
            ip0[node] = start + p0;
            ip1[node] = start + p1;
            c0a[node] = (unsigned short)(e0 - p0);
            c1a[node] = (unsigned short)(e1 - p1);
        }
    }
}

// ---------------------------------------------------------------------------
// Per-src-bucket out-degree counts from the byte-binned entries.
// ---------------------------------------------------------------------------
__global__ __launch_bounds__(512) void countO_kernel(const unsigned char* __restrict__ binnedS,
                                                     const int* __restrict__ OFS,
                                                     int* __restrict__ cntO0,
                                                     int* __restrict__ cntO1) {
    __shared__ int cnt[256];
    int t = threadIdx.x;
    int b = blockIdx.x;
    int start = OFS[HIST_L + b * NCHUNK] - TOTAL_E;
    int end = OFS[HIST_L + (b + 1) * NCHUNK] - TOTAL_E;
    if (t < 256) cnt[t] = 0;
    __syncthreads();
    for (int i = start + t; i < end; i += 512)
        atomicAdd(&cnt[(int)binnedS[i]], 1);
    __syncthreads();
    if (t < 128) {
        int node = b * 128 + t;
        if (node < N_NODES) {
            cntO0[node] = cnt[t];
            cntO1[node] = cnt[t | 128];
        }
    }
}

// ---------------------------------------------------------------------------
// Pre-split W into bf16 hi/lo MFMA B-fragments, per-lane contiguous order.
// ---------------------------------------------------------------------------
__global__ void wprep_kernel(const float* __restrict__ W0,
                             const float* __restrict__ W1,
                             short* __restrict__ Wf) {
    int t = blockIdx.x * blockDim.x + threadIdx.x;
    if (t >= 2 * 4096) return;
    int rel = t >> 12;
    int e = t & 4095;
    int k = e >> 6, col = e & 63;
    float wv = (rel ? W1 : W0)[e];
    unsigned short hi = f32_bf16_rne(wv);
    unsigned short lo = f32_bf16_rne(wv - bf16_f32(hi));
    int kstep = k >> 5, g = (k >> 3) & 3, j = k & 7;
    int base = ((((rel * 2 + 0) * 2 + kstep) * 4 + g) * 64 + col) * 8 + j;
    int baseL = ((((rel * 2 + 1) * 2 + kstep) * 4 + g) * 64 + col) * 8 + j;
    Wf[base] = (short)hi;
    Wf[baseL] = (short)lo;
}

// ---------------------------------------------------------------------------
// MFMA linears: Y0 = (X@W0)*rsqrt(degO0), Y1 = (X@W1)*rsqrt(degO1), fp16 out.
// Split-bf16 (hi+lo, 3 MFMAs). 128 rows/block, 4 waves, 2 m-tiles/wave.
// ---------------------------------------------------------------------------
__global__ __launch_bounds__(256) void lin2m_kernel(const float* __restrict__ x,
                                                    const short* __restrict__ Wf,
                                                    const int* __restrict__ cntO0,
                                                    const int* __restrict__ cntO1,
                                                    __half* __restrict__ y0,
                                                    __half* __restrict__ y1) {
    int t = threadIdx.x;
    int w = t >> 6, lane = t & 63;
    int lr = lane & 15, g = lane >> 4;
    int rowbase = blockIdx.x * 128 + w * 32;

    bf16x8 ah[2][2], al[2][2];
#pragma unroll
    for (int m = 0; m < 2; ++m) {
        int row = rowbase + m * 16 + lr;
        bool ok = row < N_NODES;
        const float* xp = x + (size_t)row * 64 + g * 8;
#pragma unroll
        for (int s = 0; s < 2; ++s) {
            float fv[8];
            if (ok) {
                float4 f0 = ((const float4*)(xp + s * 32))[0];
                float4 f1 = ((const float4*)(xp + s * 32))[1];
                fv[0] = f0.x; fv[1] = f0.y; fv[2] = f0.z; fv[3] = f0.w;
                fv[4] = f1.x; fv[5] = f1.y; fv[6] = f1.z; fv[7] = f1.w;
            } else {
#pragma unroll
                for (int j = 0; j < 8; ++j) fv[j] = 0.f;
            }
#pragma unroll
            for (int j = 0; j < 8; ++j) {
                unsigned short hi = f32_bf16_rne(fv[j]);
                unsigned short lo = f32_bf16_rne(fv[j] - bf16_f32(hi));
                ah[m][s][j] = (short)hi;
                al[m][s][j] = (short)lo;
            }
        }
    }

    float rsc[2][2][4];
#pragma unroll
    for (int m = 0; m < 2; ++m)
#pragma unroll
        for (int reg = 0; reg < 4; ++reg) {
            int row = rowbase + m * 16 + g * 4 + reg;
            bool ok = row < N_NODES;
            rsc[0][m][reg] = ok ? rsqrtf((float)max(cntO0[row], 1)) : 1.f;
            rsc[1][m][reg] = ok ? rsqrtf((float)max(cntO1[row], 1)) : 1.f;
        }

#pragma unroll
    for (int rel = 0; rel < 2; ++rel) {
        __half* yo = rel ? y1 : y0;
        const short* wr = Wf + rel * 8192 + g * 512;
#pragma unroll
        for (int n = 0; n < 4; ++n) {
            const short* wb = wr + (n * 16 + lr) * 8;
            bf16x8 wh0 = *(const bf16x8*)(wb);          // hl=0, kstep=0
            bf16x8 wh1 = *(const bf16x8*)(wb + 2048);   // hl=0, kstep=1
            bf16x8 wl0 = *(const bf16x8*)(wb + 4096);   // hl=1, kstep=0
            bf16x8 wl1 = *(const bf16x8*)(wb + 6144);   // hl=1, kstep=1
#pragma unroll
            for (int m = 0; m < 2; ++m) {
                f32x4 acc = {0.f, 0.f, 0.f, 0.f};
                acc = __builtin_amdgcn_mfma_f32_16x16x32_bf16(al[m][0], wh0, acc, 0, 0, 0);
                acc = __builtin_amdgcn_mfma_f32_16x16x32_bf16(ah[m][0], wl0, acc, 0, 0, 0);
                acc = __builtin_amdgcn_mfma_f32_16x16x32_bf16(ah[m][0], wh0, acc, 0, 0, 0);
                acc = __builtin_amdgcn_mfma_f32_16x16x32_bf16(al[m][1], wh1, acc, 0, 0, 0);
                acc = __builtin_amdgcn_mfma_f32_16x16x32_bf16(ah[m][1], wl1, acc, 0, 0, 0);
                acc = __builtin_amdgcn_mfma_f32_16x16x32_bf16(ah[m][1], wh1, acc, 0, 0, 0);
#pragma unroll
                for (int reg = 0; reg < 4; ++reg) {
                    int row = rowbase + m * 16 + g * 4 + reg;
                    if (row < N_NODES)
                        yo[(size_t)row * 64 + n * 16 + lr] =
                            __float2half_rn(acc[reg] * rsc[rel][m][reg]);
                }
            }
        }
    }
}

// ---------------------------------------------------------------------------
// Gather-aggregate: one 8-LANE GROUP per dst node, unrolled x2 with dual
// accumulators (2 independent row-loads in flight per group). Segments are
// src-sorted. No cross-lane reduction; every lane owns 8 dims.
// OUTH=0 -> f32 out (layer-1 h); OUTH=1 -> fp16 out (h2).
// ---------------------------------------------------------------------------
template <int RELU, int OUTH>
__global__ __launch_bounds__(256) void aggC_kernel(const __half* __restrict__ L0,
                                                   const __half* __restrict__ L1,
                                                   const unsigned* __restrict__ es,
                                                   const int* __restrict__ ip0,
                                                   const int* __restrict__ ip1,
                                                   const unsigned short* __restrict__ c0a,
                                                   const unsigned short* __restrict__ c1a,
                                                   const float* __restrict__ bia0,
                                                   const float* __restrict__ bia1,
                                                   float* __restrict__ outf,
                                                   __half* __restrict__ outh) {
    int t = threadIdx.x;
    int g = t >> 3, l8 = t & 7;
    int node = blockIdx.x * 32 + g;
    if (node >= N_NODES) return;

    int st0 = ip0[node], c0 = c0a[node];
    int st1 = ip1[node], c1 = c1a[node];

    float a[8] = {0, 0, 0, 0, 0, 0, 0, 0};
    float a2[8] = {0, 0, 0, 0, 0, 0, 0, 0};
    float b[8] = {0, 0, 0, 0, 0, 0, 0, 0};
    float b2[8] = {0, 0, 0, 0, 0, 0, 0, 0};
    union HU { uint4 u; __half2 h[4]; };

    int k = 0;
    for (; k + 2 <= c0; k += 2) {
        int sA = (int)es[st0 + k];
        int sB = (int)es[st0 + k + 1];
        HU uA, uB;
        uA.u = ((const uint4*)(L0 + (size_t)sA * 64))[l8];
        uB.u = ((const uint4*)(L0 + (size_t)sB * 64))[l8];
#pragma unroll
        for (int q = 0; q < 4; ++q) {
            float2 fA = __half22float2(uA.h[q]);
            float2 fB = __half22float2(uB.h[q]);
            a[2 * q] += fA.x;  a[2 * q + 1] += fA.y;
            a2[2 * q] += fB.x; a2[2 * q + 1] += fB.y;
        }
    }
    if (k < c0) {
        int s = (int)es[st0 + k];
        HU uu;
        uu.u = ((const uint4*)(L0 + (size_t)s * 64))[l8];
#pragma unroll
        for (int q = 0; q < 4; ++q) {
            float2 f = __half22float2(uu.h[q]);
            a[2 * q] += f.x;
            a[2 * q + 1] += f.y;
        }
    }
    k = 0;
    for (; k + 2 <= c1; k += 2) {
        int sA = (int)es[st1 + k];
        int sB = (int)es[st1 + k + 1];
        HU uA, uB;
        uA.u = ((const uint4*)(L1 + (size_t)sA * 64))[l8];
        uB.u = ((const uint4*)(L1 + (size_t)sB * 64))[l8];
#pragma unroll
        for (int q = 0; q < 4; ++q) {
            float2 fA = __half22float2(uA.h[q]);
            float2 fB = __half22float2(uB.h[q]);
            b[2 * q] += fA.x;  b[2 * q + 1] += fA.y;
            b2[2 * q] += fB.x; b2[2 * q + 1] += fB.y;
        }
    }
    if (k < c1) {
        int s = (int)es[st1 + k];
        HU uu;
        uu.u = ((const uint4*)(L1 + (size_t)s * 64))[l8];
#pragma unroll
        for (int q = 0; q < 4; ++q) {
            float2 f = __half22float2(uu.h[q]);
            b[2 * q] += f.x;
            b[2 * q + 1] += f.y;
        }
    }

    float r0 = rsqrtf((float)max(c0, 1));
    float r1 = rsqrtf((float)max(c1, 1));
    float4 u0a = ((const float4*)bia0)[l8 * 2];
    float4 u0b = ((const float4*)bia0)[l8 * 2 + 1];
    float4 u1a = ((const float4*)bia1)[l8 * 2];
    float4 u1b = ((const float4*)bia1)[l8 * 2 + 1];
    float o[8];
#pragma unroll
    for (int q = 0; q < 8; ++q) o[q] = (a[q] + a2[q]) * r0 + (b[q] + b2[q]) * r1;
    o[0] += u0a.x + u1a.x; o[1] += u0a.y + u1a.y;
    o[2] += u0a.z + u1a.z; o[3] += u0a.w + u1a.w;
    o[4] += u0b.x + u1b.x; o[5] += u0b.y + u1b.y;
    o[6] += u0b.z + u1b.z; o[7] += u0b.w + u1b.w;
    if (RELU) {
#pragma unroll
        for (int q = 0; q < 8; ++q) o[q] = fmaxf(o[q], 0.f);
    }
    if (OUTH) {
        HU vv;
#pragma unroll
        for (int q = 0; q < 4; ++q)
            vv.h[q] = __floats2half2_rn(o[2 * q], o[2 * q + 1]);
        ((uint4*)(outh + (size_t)node * 64))[l8] = vv.u;
    } else {
        float4 f0 = {o[0], o[1], o[2], o[3]};
        float4 f1 = {o[4], o[5], o[6], o[7]};
        ((float4*)(outf + (size_t)node * 64))[l8 * 2] = f0;
        ((float4*)(outf + (size_t)node * 64))[l8 * 2 + 1] = f1;
    }
}

// ---------------------------------------------------------------------------
// Edge dot products on fp16 h2: 8 threads per TWO edges (4 independent 16B
// loads per thread for MLP), f32 accumulate, float2 store from lane 0.
// ---------------------------------------------------------------------------
__global__ __launch_bounds__(256) void score_kernel(const __half* __restrict__ h2,
                                                    const int* __restrict__ ps,
                                                    const int* __restrict__ pd,
                                                    const int* __restrict__ ns,
                                                    const int* __restrict__ nd,
                                                    float* __restrict__ out) {
    int gid = blockIdx.x * blockDim.x + threadIdx.x;
    int pr = gid >> 3;
    int l8 = gid & 7;
    int e0 = pr * 2;
    if (e0 >= TOTAL_E) return;
    int e1 = e0 + 1;   // pairs never straddle the pos/neg boundary (N_EDGES even)
    int sA, dA, sB, dB;
    if (e0 < N_EDGES) { sA = ps[e0]; dA = pd[e0]; sB = ps[e1]; dB = pd[e1]; }
    else {
        sA = ns[e0 - N_EDGES]; dA = nd[e0 - N_EDGES];
        sB = ns[e1 - N_EDGES]; dB = nd[e1 - N_EDGES];
    }
    union HU { uint4 u; __half2 h[4]; };
    HU ua0, ub0, ua1, ub1;
    ua0.u = ((const uint4*)(h2 + (size_t)sA * 64))[l8];
    ub0.u = ((const uint4*)(h2 + (size_t)dA * 64))[l8];
    ua1.u = ((const uint4*)(h2 + (size_t)sB * 64))[l8];
    ub1.u = ((const uint4*)(h2 + (size_t)dB * 64))[l8];
    float p0 = 0.f, p1 = 0.f;
#pragma unroll
    for (int q = 0; q < 4; ++q) {
        float2 fa0 = __half22float2(ua0.h[q]);
        float2 fb0 = __half22float2(ub0.h[q]);
        float2 fa1 = __half22float2(ua1.h[q]);
        float2 fb1 = __half22float2(ub1.h[q]);
        p0 += fa0.x * fb0.x + fa0.y * fb0.y;
        p1 += fa1.x * fb1.x + fa1.y * fb1.y;
    }
    p0 += __shfl_xor(p0, 1);
    p0 += __shfl_xor(p0, 2);
    p0 += __shfl_xor(p0, 4);
    p1 += __shfl_xor(p1, 1);
    p1 += __shfl_xor(p1, 2);
    p1 += __shfl_xor(p1, 4);
    if (l8 == 0) ((float2*)out)[pr] = make_float2(p0, p1);
}

extern "C" void kernel_launch(void* const* d_in, const int* in_sizes, int n_in,
                              void* d_out, int out_size, void* d_ws, size_t ws_size,
                              hipStream_t stream) {
    const float* x    = (const float*)d_in[0];
    const int* s0     = (const int*)d_in[1];
    const int* d0     = (const int*)d_in[2];
    const int* s1     = (const int*)d_in[3];
    const int* d1     = (const int*)d_in[4];
    const int* nsrc   = (const int*)d_in[5];
    const int* ndst   = (const int*)d_in[6];
    const float* W1_0 = (const float*)d_in[7];
    const float* W1_1 = (const float*)d_in[8];
    const float* W2_0 = (const float*)d_in[9];
    const float* W2_1 = (const float*)d_in[10];
    const float* b1_0 = (const float*)d_in[11];
    const float* b1_1 = (const float*)d_in[12];
    const float* b2_0 = (const float*)d_in[13];
    const float* b2_1 = (const float*)d_in[14];
    float* out = (float*)d_out;

    // ---- workspace ----
    char* p = (char*)d_ws;
    int* cntO0 = (int*)p;      p += N_NODES * 4;
    int* cntO1 = (int*)p;      p += N_NODES * 4;
    int* hist  = (int*)p;      p += (size_t)HIST2 * 4;
    int* OFS   = (int*)p;      p += ((size_t)HIST2 + 8) * 4;
    int* bsum  = (int*)p;      p += 2048 * 4;
    unsigned* binned = (unsigned*)p;  p += (size_t)TOTAL_E * 4;
    int* ip0   = (int*)p;      p += N_NODES * 4;
    int* ip1   = (int*)p;      p += N_NODES * 4;
    unsigned short* c0a = (unsigned short*)p;  p += N_NODES * 2;
    unsigned short* c1a = (unsigned short*)p;  p += N_NODES * 2;
    unsigned char* binnedS = (unsigned char*)p;  p += (size_t)TOTAL_E;
    p = (char*)(((size_t)p + 255) & ~(size_t)255);
    short* WfA = (short*)p;    p += 16384 * 2;               // layer-1 W frags
    short* WfB = (short*)p;    p += 16384 * 2;               // layer-2 W frags
    p = (char*)(((size_t)p + 255) & ~(size_t)255);
    __half* bufL0h = (__half*)p;  p += (size_t)N_NODES * D * 2;
    __half* bufL1h = (__half*)p;  p += (size_t)N_NODES * D * 2;
    __half* h2h    = (__half*)p;  p += (size_t)N_NODES * D * 2;
    p = (char*)(((size_t)p + 255) & ~(size_t)255);
    float* bufH = (float*)p;   p += (size_t)N_NODES * D * 4;

    const int aggGrid  = (N_NODES + 31) / 32;
    const int scorGrid = (TOTAL_E / 2 * 8 + 255) / 256;

    // ---- W fragment prep (tiny) ----
    wprep_kernel<<<32, 256, 0, stream>>>(W1_0, W1_1, WfA);
    wprep_kernel<<<32, 256, 0, stream>>>(W2_0, W2_1, WfB);

    // ---- degrees + binning (no per-edge global atomics anywhere) ----
    countA_kernel<<<NCHUNK, 512, 0, stream>>>(s0, d0, s1, d1, hist);
    scan1_kernel<<<SCAN_NB2, SCAN_BS, 0, stream>>>(hist, OFS, bsum);
    scan2_kernel<<<1, 1024, 0, stream>>>(bsum);
    scan3_kernel<<<SCAN_NB2, SCAN_BS, 0, stream>>>(OFS, bsum);
    scatterA_kernel<<<NCHUNK, 512, 0, stream>>>(s0, d0, s1, d1, OFS, binned, binnedS);
    sortB_kernel<<<NBUCK, 512, 0, stream>>>(binned, OFS, ip0, ip1, c0a, c1a);
    countO_kernel<<<NBUCK, 512, 0, stream>>>(binnedS, OFS, cntO0, cntO1);

    // ---- layer 1 ----
    lin2m_kernel<<<L2M_GRID, 256, 0, stream>>>(x, WfA, cntO0, cntO1, bufL0h, bufL1h);
    aggC_kernel<1, 0><<<aggGrid, 256, 0, stream>>>(bufL0h, bufL1h, binned, ip0, ip1,
                                                   c0a, c1a, b1_0, b1_1, bufH, nullptr);

    // ---- layer 2 ----
    lin2m_kernel<<<L2M_GRID, 256, 0, stream>>>(bufH, WfB, cntO0, cntO1, bufL0h, bufL1h);
    aggC_kernel<0, 1><<<aggGrid, 256, 0, stream>>>(bufL0h, bufL1h, binned, ip0, ip1,
                                                   c0a, c1a, b2_0, b2_1, nullptr, h2h);

    // ---- scores ----
    score_kernel<<<scorGrid, 256, 0, stream>>>(h2h, s0, d0, nsrc, ndst, out);
}

// Round 6
// 273.302 us; speedup vs baseline: 8.2011x; 1.0972x over previous
//
#include <hip/hip_runtime.h>
#include <hip/hip_fp16.h>

#define N_NODES 100000
#define N_EDGES 1200000
#define TOTAL_E (2 * N_EDGES)
#define D 64

#define BSH 7                       // bucket = node >> 7 (128 nodes/bucket)
#define NBUCK 782                   // ceil(100000/128)
#define NCHUNK 320
#define CHUNK 7500                  // NCHUNK * CHUNK == TOTAL_E
#define HIST_L (NBUCK * NCHUNK)     // 250240 (per side)
#define HIST2 (2 * HIST_L)          // 500480 (dst half + src half, one scan)
#define SCAN_BS 256
#define SCAN_NB2 ((HIST2 + SCAN_BS - 1) / SCAN_BS)  // 1955
#define ENT_CAP 4608                // bucket mean 3072, sigma 55 -> +28 sigma
#define L2M_GRID ((N_NODES + 127) / 128)  // 782
#define NKEY 2048                   // sortB key: rel(1) | dl(7) | src_super(3)

typedef __attribute__((ext_vector_type(8))) short bf16x8;
typedef __attribute__((ext_vector_type(4))) float f32x4;

__device__ __forceinline__ unsigned short f32_bf16_rne(float f) {
    unsigned u = __float_as_uint(f);
    unsigned r = u + 0x7FFF + ((u >> 16) & 1);
    return (unsigned short)(r >> 16);
}
__device__ __forceinline__ float bf16_f32(unsigned short h) {
    return __uint_as_float(((unsigned)h) << 16);
}

// ---------------------------------------------------------------------------
// Per-chunk LDS histograms of dst buckets AND src buckets. No global atomics.
// hist layout: [0, HIST_L) = dst-side, [HIST_L, HIST2) = src-side.
// ---------------------------------------------------------------------------
__global__ __launch_bounds__(512) void countA_kernel(const int* __restrict__ s0,
                                                     const int* __restrict__ d0,
                                                     const int* __restrict__ s1,
                                                     const int* __restrict__ d1,
                                                     int* __restrict__ hist) {
    __shared__ int hD[NBUCK];
    __shared__ int hS[NBUCK];
    int t = threadIdx.x;
    for (int i = t; i < NBUCK; i += 512) { hD[i] = 0; hS[i] = 0; }
    __syncthreads();
    int base = blockIdx.x * CHUNK;
    for (int i = t; i < CHUNK; i += 512) {
        int e = base + i;
        int rel = (e >= N_EDGES);
        int src = rel ? s1[e - N_EDGES] : s0[e];
        int dst = rel ? d1[e - N_EDGES] : d0[e];
        atomicAdd(&hD[dst >> BSH], 1);
        atomicAdd(&hS[src >> BSH], 1);
    }
    __syncthreads();
    for (int i = t; i < NBUCK; i += 512) {
        hist[i * NCHUNK + blockIdx.x] = hD[i];
        hist[HIST_L + i * NCHUNK + blockIdx.x] = hS[i];
    }
}

// ---------------------------------------------------------------------------
// ONE exclusive scan over HIST2 ints (dst+src halves contiguous).
// Src-side offsets are OFS[HIST_L + i] - TOTAL_E.
// ---------------------------------------------------------------------------
__global__ void scan1_kernel(const int* __restrict__ in, int* __restrict__ out,
                             int* __restrict__ bsum) {
    __shared__ int s[SCAN_BS];
    int t = threadIdx.x;
    int i = blockIdx.x * SCAN_BS + t;
    int v = (i < HIST2) ? in[i] : 0;
    s[t] = v;
    __syncthreads();
    for (int off = 1; off < SCAN_BS; off <<= 1) {
        int add = (t >= off) ? s[t - off] : 0;
        __syncthreads();
        s[t] += add;
        __syncthreads();
    }
    if (i < HIST2) out[i] = s[t] - v;
    if (t == SCAN_BS - 1) bsum[blockIdx.x] = s[t];
}

__global__ void scan2_kernel(int* __restrict__ bsum) {
    __shared__ int s[1024];
    int t = threadIdx.x;
    int v0 = (2 * t < SCAN_NB2) ? bsum[2 * t] : 0;
    int v1 = (2 * t + 1 < SCAN_NB2) ? bsum[2 * t + 1] : 0;
    int sum = v0 + v1;
    s[t] = sum;
    __syncthreads();
    for (int off = 1; off < 1024; off <<= 1) {
        int add = (t >= off) ? s[t - off] : 0;
        __syncthreads();
        s[t] += add;
        __syncthreads();
    }
    int ex = s[t] - sum;
    if (2 * t < SCAN_NB2) bsum[2 * t] = ex;
    if (2 * t + 1 < SCAN_NB2) bsum[2 * t + 1] = ex + v0;
}

__global__ void scan3_kernel(int* __restrict__ out, const int* __restrict__ bsum) {
    int i = blockIdx.x * SCAN_BS + threadIdx.x;
    if (i < HIST2) out[i] += bsum[blockIdx.x];
    if (i == 0) out[HIST2] = 2 * TOTAL_E;
}

// ---------------------------------------------------------------------------
// Scatter with LDS counting-sort + coalesced run-flush (kills the ~150 MB
// write-through amplification of per-lane scattered 4B/1B stores).
// Phase A-D: dst-bucket sort -> binned (u32 entries, bucket-run coalesced).
// Phase E-J: src-bucket rank  -> binnedS (u8 entries, run coalesced).
// dst entry (u32) = src | dl<<17 | rel<<24; src entry (u8) = sl | rel<<7.
// ---------------------------------------------------------------------------
__global__ __launch_bounds__(512) void scatterA_kernel(const int* __restrict__ s0,
                                                       const int* __restrict__ d0,
                                                       const int* __restrict__ s1,
                                                       const int* __restrict__ d1,
                                                       const int* __restrict__ OFS,
                                                       unsigned* __restrict__ binned,
                                                       unsigned char* __restrict__ binnedS) {
    __shared__ unsigned ent[CHUNK];          // entries in dst-bucket-sorted order
    __shared__ unsigned short kent[CHUNK];   // dst bucket per sorted slot; later src-rank idx
    __shared__ int cnt[NBUCK], pfx[NBUCK], cur[NBUCK];
    __shared__ int tsum[512];
    int t = threadIdx.x, wg = blockIdx.x;
    int base = wg * CHUNK;

    // A: dst-bucket histogram
    for (int b = t; b < NBUCK; b += 512) cnt[b] = 0;
    __syncthreads();
    for (int i = t; i < CHUNK; i += 512) {
        int e = base + i;
        int rel = (e >= N_EDGES);
        int dst = rel ? d1[e - N_EDGES] : d0[e];
        atomicAdd(&cnt[dst >> BSH], 1);
    }
    __syncthreads();
    // B: exclusive scan cnt -> pfx (2 buckets/thread + 512-wide Hillis-Steele)
    {
        int b2 = t * 2;
        int k0 = (b2 < NBUCK) ? cnt[b2] : 0;
        int k1 = (b2 + 1 < NBUCK) ? cnt[b2 + 1] : 0;
        int sum = k0 + k1;
        tsum[t] = sum;
        __syncthreads();
        for (int off = 1; off < 512; off <<= 1) {
            int add = (t >= off) ? tsum[t - off] : 0;
            __syncthreads();
            tsum[t] += add;
            __syncthreads();
        }
        int ex = tsum[t] - sum;
        if (b2 < NBUCK) pfx[b2] = ex;
        if (b2 + 1 < NBUCK) pfx[b2 + 1] = ex + k0;
    }
    __syncthreads();
    // B2: cur = pfx; cnt <- global dst-side bases for this chunk
    for (int b = t; b < NBUCK; b += 512) {
        cur[b] = pfx[b];
        cnt[b] = OFS[b * NCHUNK + wg];
    }
    __syncthreads();
    // C: re-read edges, rank, place into LDS in sorted order
    for (int i = t; i < CHUNK; i += 512) {
        int e = base + i;
        int rel = (e >= N_EDGES);
        int src = rel ? s1[e - N_EDGES] : s0[e];
        int dst = rel ? d1[e - N_EDGES] : d0[e];
        int kb = dst >> BSH;
        unsigned u = (unsigned)src | ((unsigned)(dst & 127) << 17) | ((unsigned)rel << 24);
        int r = atomicAdd(&cur[kb], 1);
        ent[r] = u;
        kent[r] = (unsigned short)kb;
    }
    __syncthreads();
    // D: coalesced flush of binned (consecutive j -> consecutive p within runs)
    for (int j = t; j < CHUNK; j += 512) {
        int kb = (int)kent[j];
        binned[cnt[kb] + (j - pfx[kb])] = ent[j];
    }
    __syncthreads();
    // E/F: src-bucket histogram from staged entries
    for (int b = t; b < NBUCK; b += 512) cnt[b] = 0;
    __syncthreads();
    for (int i = t; i < CHUNK; i += 512)
        atomicAdd(&cnt[(int)(ent[i] & 0x1FFFFu) >> BSH], 1);
    __syncthreads();
    // G: scan
    {
        int b2 = t * 2;
        int k0 = (b2 < NBUCK) ? cnt[b2] : 0;
        int k1 = (b2 + 1 < NBUCK) ? cnt[b2 + 1] : 0;
        int sum = k0 + k1;
        tsum[t] = sum;
        __syncthreads();
        for (int off = 1; off < 512; off <<= 1) {
            int add = (t >= off) ? tsum[t - off] : 0;
            __syncthreads();
            tsum[t] += add;
            __syncthreads();
        }
        int ex = tsum[t] - sum;
        if (b2 < NBUCK) pfx[b2] = ex;
        if (b2 + 1 < NBUCK) pfx[b2 + 1] = ex + k0;
    }
    __syncthreads();
    // H: cur = pfx; cnt <- global src-side bases for this chunk
    for (int b = t; b < NBUCK; b += 512) {
        cur[b] = pfx[b];
        cnt[b] = OFS[HIST_L + b * NCHUNK + wg] - TOTAL_E;
    }
    __syncthreads();
    // I: src rank -> inverse index in kent (kent free after D)
    for (int i = t; i < CHUNK; i += 512) {
        int kS = (int)(ent[i] & 0x1FFFFu) >> BSH;
        int r = atomicAdd(&cur[kS], 1);
        kent[r] = (unsigned short)i;
    }
    __syncthreads();
    // J: coalesced byte flush of binnedS
    for (int j = t; j < CHUNK; j += 512) {
        unsigned u = ent[(int)kent[j]];
        int kS = (int)(u & 0x1FFFFu) >> BSH;
        binnedS[cnt[kS] + (j - pfx[kS])] =
            (unsigned char)((u & 127) | (((u >> 24) & 1) << 7));
    }
}

// ---------------------------------------------------------------------------
// Per-bucket LDS counting sort (in place): binned -> src indices grouped by
// key = rel<<10 | dl<<3 | src_super (src_super = src>>14, 0..6).
// ---------------------------------------------------------------------------
__global__ __launch_bounds__(512) void sortB_kernel(unsigned* __restrict__ binned,
                                                    const int* __restrict__ OFS,
                                                    int* __restrict__ ip0,
                                                    int* __restrict__ ip1,
                                                    unsigned short* __restrict__ c0a,
                                                    unsigned short* __restrict__ c1a) {
    __shared__ unsigned ent[ENT_CAP];
    __shared__ int cnt[NKEY], pfx[NKEY], cur[NKEY];
    __shared__ int tsum[512];
    int t = threadIdx.x;
    int b = blockIdx.x;
    int start = OFS[b * NCHUNK];
    int end = OFS[(b + 1) * NCHUNK];
    int n = end - start;

    for (int i = t; i < NKEY; i += 512) cnt[i] = 0;
    __syncthreads();
    for (int i = t; i < n; i += 512) {
        unsigned u = binned[start + i];
        if (i < ENT_CAP) ent[i] = u;
        int key = ((int)((u >> 17) & 255) << 3) | (int)((u & 0x1FFFFu) >> 14);
        atomicAdd(&cnt[key], 1);
    }
    __syncthreads();
    int b4 = t * 4;
    int k0 = cnt[b4], k1 = cnt[b4 + 1], k2 = cnt[b4 + 2], k3 = cnt[b4 + 3];
    int s1 = k0 + k1, s2 = s1 + k2, s3 = s2 + k3;
    tsum[t] = s3;
    __syncthreads();
    for (int off = 1; off < 512; off <<= 1) {
        int add = (t >= off) ? tsum[t - off] : 0;
        __syncthreads();
        tsum[t] += add;
        __syncthreads();
    }
    int ex = tsum[t] - s3;
    pfx[b4] = ex;
    pfx[b4 + 1] = ex + k0;
    pfx[b4 + 2] = ex + s1;
    pfx[b4 + 3] = ex + s2;
    cur[b4] = ex;
    cur[b4 + 1] = ex + k0;
    cur[b4 + 2] = ex + s1;
    cur[b4 + 3] = ex + s2;
    __syncthreads();
    for (int i = t; i < n; i += 512) {
        if (i < ENT_CAP) {
            unsigned u = ent[i];
            int key = ((int)((u >> 17) & 255) << 3) | (int)((u & 0x1FFFFu) >> 14);
            int p = atomicAdd(&cur[key], 1);
            binned[start + p] = u & 0x1FFFF;
        }
    }
    if (t < 128) {
        int node = b * 128 + t;
        if (node < N_NODES) {
            int kr0 = t << 3;
            int kr1 = (1 << 10) | (t << 3);
            int p0 = pfx[kr0];
            int e0 = pfx[kr0 + 8];
            int p1 = pfx[kr1];
            int e1 = (t == 127) ? n : pfx[kr1 + 8];
            ip0[node] = start + p0;
            ip1[node] = start + p1;
            c0a[node] = (unsigned short)(e0 - p0);
            c1a[node] = (unsigned short)(e1 - p1);
        }
    }
}

// ---------------------------------------------------------------------------
// Per-src-bucket out-degree counts from the byte-binned entries.
// ---------------------------------------------------------------------------
__global__ __launch_bounds__(512) void countO_kernel(const unsigned char* __restrict__ binnedS,
                                                     const int* __restrict__ OFS,
                                                     int* __restrict__ cntO0,
                                                     int* __restrict__ cntO1) {
    __shared__ int cnt[256];
    int t = threadIdx.x;
    int b = blockIdx.x;
    int start = OFS[HIST_L + b * NCHUNK] - TOTAL_E;
    int end = OFS[HIST_L + (b + 1) * NCHUNK] - TOTAL_E;
    if (t < 256) cnt[t] = 0;
    __syncthreads();
    for (int i = start + t; i < end; i += 512)
        atomicAdd(&cnt[(int)binnedS[i]], 1);
    __syncthreads();
    if (t < 128) {
        int node = b * 128 + t;
        if (node < N_NODES) {
            cntO0[node] = cnt[t];
            cntO1[node] = cnt[t | 128];
        }
    }
}

// ---------------------------------------------------------------------------
// Pre-split W into bf16 hi/lo MFMA B-fragments, per-lane contiguous order.
// ---------------------------------------------------------------------------
__global__ void wprep_kernel(const float* __restrict__ W0,
                             const float* __restrict__ W1,
                             short* __restrict__ Wf) {
    int t = blockIdx.x * blockDim.x + threadIdx.x;
    if (t >= 2 * 4096) return;
    int rel = t >> 12;
    int e = t & 4095;
    int k = e >> 6, col = e & 63;
    float wv = (rel ? W1 : W0)[e];
    unsigned short hi = f32_bf16_rne(wv);
    unsigned short lo = f32_bf16_rne(wv - bf16_f32(hi));
    int kstep = k >> 5, g = (k >> 3) & 3, j = k & 7;
    int base = ((((rel * 2 + 0) * 2 + kstep) * 4 + g) * 64 + col) * 8 + j;
    int baseL = ((((rel * 2 + 1) * 2 + kstep) * 4 + g) * 64 + col) * 8 + j;
    Wf[base] = (short)hi;
    Wf[baseL] = (short)lo;
}

// ---------------------------------------------------------------------------
// MFMA linears: Y0 = (X@W0)*rsqrt(degO0), Y1 = (X@W1)*rsqrt(degO1), fp16 out.
// Split-bf16 (hi+lo, 3 MFMAs). 128 rows/block, 4 waves, 2 m-tiles/wave.
// ---------------------------------------------------------------------------
__global__ __launch_bounds__(256) void lin2m_kernel(const float* __restrict__ x,
                                                    const short* __restrict__ Wf,
                                                    const int* __restrict__ cntO0,
                                                    const int* __restrict__ cntO1,
                                                    __half* __restrict__ y0,
                                                    __half* __restrict__ y1) {
    int t = threadIdx.x;
    int w = t >> 6, lane = t & 63;
    int lr = lane & 15, g = lane >> 4;
    int rowbase = blockIdx.x * 128 + w * 32;

    bf16x8 ah[2][2], al[2][2];
#pragma unroll
    for (int m = 0; m < 2; ++m) {
        int row = rowbase + m * 16 + lr;
        bool ok = row < N_NODES;
        const float* xp = x + (size_t)row * 64 + g * 8;
#pragma unroll
        for (int s = 0; s < 2; ++s) {
            float fv[8];
            if (ok) {
                float4 f0 = ((const float4*)(xp + s * 32))[0];
                float4 f1 = ((const float4*)(xp + s * 32))[1];
                fv[0] = f0.x; fv[1] = f0.y; fv[2] = f0.z; fv[3] = f0.w;
                fv[4] = f1.x; fv[5] = f1.y; fv[6] = f1.z; fv[7] = f1.w;
            } else {
#pragma unroll
                for (int j = 0; j < 8; ++j) fv[j] = 0.f;
            }
#pragma unroll
            for (int j = 0; j < 8; ++j) {
                unsigned short hi = f32_bf16_rne(fv[j]);
                unsigned short lo = f32_bf16_rne(fv[j] - bf16_f32(hi));
                ah[m][s][j] = (short)hi;
                al[m][s][j] = (short)lo;
            }
        }
    }

    float rsc[2][2][4];
#pragma unroll
    for (int m = 0; m < 2; ++m)
#pragma unroll
        for (int reg = 0; reg < 4; ++reg) {
            int row = rowbase + m * 16 + g * 4 + reg;
            bool ok = row < N_NODES;
            rsc[0][m][reg] = ok ? rsqrtf((float)max(cntO0[row], 1)) : 1.f;
            rsc[1][m][reg] = ok ? rsqrtf((float)max(cntO1[row], 1)) : 1.f;
        }

#pragma unroll
    for (int rel = 0; rel < 2; ++rel) {
        __half* yo = rel ? y1 : y0;
        const short* wr = Wf + rel * 8192 + g * 512;
#pragma unroll
        for (int n = 0; n < 4; ++n) {
            const short* wb = wr + (n * 16 + lr) * 8;
            bf16x8 wh0 = *(const bf16x8*)(wb);          // hl=0, kstep=0
            bf16x8 wh1 = *(const bf16x8*)(wb + 2048);   // hl=0, kstep=1
            bf16x8 wl0 = *(const bf16x8*)(wb + 4096);   // hl=1, kstep=0
            bf16x8 wl1 = *(const bf16x8*)(wb + 6144);   // hl=1, kstep=1
#pragma unroll
            for (int m = 0; m < 2; ++m) {
                f32x4 acc = {0.f, 0.f, 0.f, 0.f};
                acc = __builtin_amdgcn_mfma_f32_16x16x32_bf16(al[m][0], wh0, acc, 0, 0, 0);
                acc = __builtin_amdgcn_mfma_f32_16x16x32_bf16(ah[m][0], wl0, acc, 0, 0, 0);
                acc = __builtin_amdgcn_mfma_f32_16x16x32_bf16(ah[m][0], wh0, acc, 0, 0, 0);
                acc = __builtin_amdgcn_mfma_f32_16x16x32_bf16(al[m][1], wh1, acc, 0, 0, 0);
                acc = __builtin_amdgcn_mfma_f32_16x16x32_bf16(ah[m][1], wl1, acc, 0, 0, 0);
                acc = __builtin_amdgcn_mfma_f32_16x16x32_bf16(ah[m][1], wh1, acc, 0, 0, 0);
#pragma unroll
                for (int reg = 0; reg < 4; ++reg) {
                    int row = rowbase + m * 16 + g * 4 + reg;
                    if (row < N_NODES)
                        yo[(size_t)row * 64 + n * 16 + lr] =
                            __float2half_rn(acc[reg] * rsc[rel][m][reg]);
                }
            }
        }
    }
}

// ---------------------------------------------------------------------------
// Gather-aggregate: one 8-LANE GROUP per dst node, unrolled x4 with dual
// accumulator banks (4 independent row-loads in flight per group).
// OUTH=0 -> f32 out (layer-1 h); OUTH=1 -> fp16 out (h2).
// ---------------------------------------------------------------------------
template <int RELU, int OUTH>
__global__ __launch_bounds__(256) void aggC_kernel(const __half* __restrict__ L0,
                                                   const __half* __restrict__ L1,
                                                   const unsigned* __restrict__ es,
                                                   const int* __restrict__ ip0,
                                                   const int* __restrict__ ip1,
                                                   const unsigned short* __restrict__ c0a,
                                                   const unsigned short* __restrict__ c1a,
                                                   const float* __restrict__ bia0,
                                                   const float* __restrict__ bia1,
                                                   float* __restrict__ outf,
                                                   __half* __restrict__ outh) {
    int t = threadIdx.x;
    int g = t >> 3, l8 = t & 7;
    int node = blockIdx.x * 32 + g;
    if (node >= N_NODES) return;

    int st0 = ip0[node], c0 = c0a[node];
    int st1 = ip1[node], c1 = c1a[node];

    float a[8] = {0, 0, 0, 0, 0, 0, 0, 0};
    float a2[8] = {0, 0, 0, 0, 0, 0, 0, 0};
    float b[8] = {0, 0, 0, 0, 0, 0, 0, 0};
    float b2[8] = {0, 0, 0, 0, 0, 0, 0, 0};
    union HU { uint4 u; __half2 h[4]; };

    int k = 0;
    for (; k + 4 <= c0; k += 4) {
        int sA = (int)es[st0 + k];
        int sB = (int)es[st0 + k + 1];
        int sC = (int)es[st0 + k + 2];
        int sD = (int)es[st0 + k + 3];
        HU uA, uB, uC, uD;
        uA.u = ((const uint4*)(L0 + (size_t)sA * 64))[l8];
        uB.u = ((const uint4*)(L0 + (size_t)sB * 64))[l8];
        uC.u = ((const uint4*)(L0 + (size_t)sC * 64))[l8];
        uD.u = ((const uint4*)(L0 + (size_t)sD * 64))[l8];
#pragma unroll
        for (int q = 0; q < 4; ++q) {
            float2 fA = __half22float2(uA.h[q]);
            float2 fB = __half22float2(uB.h[q]);
            float2 fC = __half22float2(uC.h[q]);
            float2 fD = __half22float2(uD.h[q]);
            a[2 * q] += fA.x + fC.x;  a[2 * q + 1] += fA.y + fC.y;
            a2[2 * q] += fB.x + fD.x; a2[2 * q + 1] += fB.y + fD.y;
        }
    }
    for (; k < c0; ++k) {
        int s = (int)es[st0 + k];
        HU uu;
        uu.u = ((const uint4*)(L0 + (size_t)s * 64))[l8];
#pragma unroll
        for (int q = 0; q < 4; ++q) {
            float2 f = __half22float2(uu.h[q]);
            a[2 * q] += f.x;
            a[2 * q + 1] += f.y;
        }
    }
    k = 0;
    for (; k + 4 <= c1; k += 4) {
        int sA = (int)es[st1 + k];
        int sB = (int)es[st1 + k + 1];
        int sC = (int)es[st1 + k + 2];
        int sD = (int)es[st1 + k + 3];
        HU uA, uB, uC, uD;
        uA.u = ((const uint4*)(L1 + (size_t)sA * 64))[l8];
        uB.u = ((const uint4*)(L1 + (size_t)sB * 64))[l8];
        uC.u = ((const uint4*)(L1 + (size_t)sC * 64))[l8];
        uD.u = ((const uint4*)(L1 + (size_t)sD * 64))[l8];
#pragma unroll
        for (int q = 0; q < 4; ++q) {
            float2 fA = __half22float2(uA.h[q]);
            float2 fB = __half22float2(uB.h[q]);
            float2 fC = __half22float2(uC.h[q]);
            float2 fD = __half22float2(uD.h[q]);
            b[2 * q] += fA.x + fC.x;  b[2 * q + 1] += fA.y + fC.y;
            b2[2 * q] += fB.x + fD.x; b2[2 * q + 1] += fB.y + fD.y;
        }
    }
    for (; k < c1; ++k) {
        int s = (int)es[st1 + k];
        HU uu;
        uu.u = ((const uint4*)(L1 + (size_t)s * 64))[l8];
#pragma unroll
        for (int q = 0; q < 4; ++q) {
            float2 f = __half22float2(uu.h[q]);
            b[2 * q] += f.x;
            b[2 * q + 1] += f.y;
        }
    }

    float r0 = rsqrtf((float)max(c0, 1));
    float r1 = rsqrtf((float)max(c1, 1));
    float4 u0a = ((const float4*)bia0)[l8 * 2];
    float4 u0b = ((const float4*)bia0)[l8 * 2 + 1];
    float4 u1a = ((const float4*)bia1)[l8 * 2];
    float4 u1b = ((const float4*)bia1)[l8 * 2 + 1];
    float o[8];
#pragma unroll
    for (int q = 0; q < 8; ++q) o[q] = (a[q] + a2[q]) * r0 + (b[q] + b2[q]) * r1;
    o[0] += u0a.x + u1a.x; o[1] += u0a.y + u1a.y;
    o[2] += u0a.z + u1a.z; o[3] += u0a.w + u1a.w;
    o[4] += u0b.x + u1b.x; o[5] += u0b.y + u1b.y;
    o[6] += u0b.z + u1b.z; o[7] += u0b.w + u1b.w;
    if (RELU) {
#pragma unroll
        for (int q = 0; q < 8; ++q) o[q] = fmaxf(o[q], 0.f);
    }
    if (OUTH) {
        HU vv;
#pragma unroll
        for (int q = 0; q < 4; ++q)
            vv.h[q] = __floats2half2_rn(o[2 * q], o[2 * q + 1]);
        ((uint4*)(outh + (size_t)node * 64))[l8] = vv.u;
    } else {
        float4 f0 = {o[0], o[1], o[2], o[3]};
        float4 f1 = {o[4], o[5], o[6], o[7]};
        ((float4*)(outf + (size_t)node * 64))[l8 * 2] = f0;
        ((float4*)(outf + (size_t)node * 64))[l8 * 2 + 1] = f1;
    }
}

// ---------------------------------------------------------------------------
// Edge dot products on fp16 h2: 8 threads per TWO edges (4 independent 16B
// loads per thread for MLP), f32 accumulate, float2 store from lane 0.
// ---------------------------------------------------------------------------
__global__ __launch_bounds__(256) void score_kernel(const __half* __restrict__ h2,
                                                    const int* __restrict__ ps,
                                                    const int* __restrict__ pd,
                                                    const int* __restrict__ ns,
                                                    const int* __restrict__ nd,
                                                    float* __restrict__ out) {
    int gid = blockIdx.x * blockDim.x + threadIdx.x;
    int pr = gid >> 3;
    int l8 = gid & 7;
    int e0 = pr * 2;
    if (e0 >= TOTAL_E) return;
    int e1 = e0 + 1;   // pairs never straddle the pos/neg boundary (N_EDGES even)
    int sA, dA, sB, dB;
    if (e0 < N_EDGES) { sA = ps[e0]; dA = pd[e0]; sB = ps[e1]; dB = pd[e1]; }
    else {
        sA = ns[e0 - N_EDGES]; dA = nd[e0 - N_EDGES];
        sB = ns[e1 - N_EDGES]; dB = nd[e1 - N_EDGES];
    }
    union HU { uint4 u; __half2 h[4]; };
    HU ua0, ub0, ua1, ub1;
    ua0.u = ((const uint4*)(h2 + (size_t)sA * 64))[l8];
    ub0.u = ((const uint4*)(h2 + (size_t)dA * 64))[l8];
    ua1.u = ((const uint4*)(h2 + (size_t)sB * 64))[l8];
    ub1.u = ((const uint4*)(h2 + (size_t)dB * 64))[l8];
    float p0 = 0.f, p1 = 0.f;
#pragma unroll
    for (int q = 0; q < 4; ++q) {
        float2 fa0 = __half22float2(ua0.h[q]);
        float2 fb0 = __half22float2(ub0.h[q]);
        float2 fa1 = __half22float2(ua1.h[q]);
        float2 fb1 = __half22float2(ub1.h[q]);
        p0 += fa0.x * fb0.x + fa0.y * fb0.y;
        p1 += fa1.x * fb1.x + fa1.y * fb1.y;
    }
    p0 += __shfl_xor(p0, 1);
    p0 += __shfl_xor(p0, 2);
    p0 += __shfl_xor(p0, 4);
    p1 += __shfl_xor(p1, 1);
    p1 += __shfl_xor(p1, 2);
    p1 += __shfl_xor(p1, 4);
    if (l8 == 0) ((float2*)out)[pr] = make_float2(p0, p1);
}

extern "C" void kernel_launch(void* const* d_in, const int* in_sizes, int n_in,
                              void* d_out, int out_size, void* d_ws, size_t ws_size,
                              hipStream_t stream) {
    const float* x    = (const float*)d_in[0];
    const int* s0     = (const int*)d_in[1];
    const int* d0     = (const int*)d_in[2];
    const int* s1     = (const int*)d_in[3];
    const int* d1     = (const int*)d_in[4];
    const int* nsrc   = (const int*)d_in[5];
    const int* ndst   = (const int*)d_in[6];
    const float* W1_0 = (const float*)d_in[7];
    const float* W1_1 = (const float*)d_in[8];
    const float* W2_0 = (const float*)d_in[9];
    const float* W2_1 = (const float*)d_in[10];
    const float* b1_0 = (const float*)d_in[11];
    const float* b1_1 = (const float*)d_in[12];
    const float* b2_0 = (const float*)d_in[13];
    const float* b2_1 = (const float*)d_in[14];
    float* out = (float*)d_out;

    // ---- workspace ----
    char* p = (char*)d_ws;
    int* cntO0 = (int*)p;      p += N_NODES * 4;
    int* cntO1 = (int*)p;      p += N_NODES * 4;
    int* hist  = (int*)p;      p += (size_t)HIST2 * 4;
    int* OFS   = (int*)p;      p += ((size_t)HIST2 + 8) * 4;
    int* bsum  = (int*)p;      p += 2048 * 4;
    unsigned* binned = (unsigned*)p;  p += (size_t)TOTAL_E * 4;
    int* ip0   = (int*)p;      p += N_NODES * 4;
    int* ip1   = (int*)p;      p += N_NODES * 4;
    unsigned short* c0a = (unsigned short*)p;  p += N_NODES * 2;
    unsigned short* c1a = (unsigned short*)p;  p += N_NODES * 2;
    unsigned char* binnedS = (unsigned char*)p;  p += (size_t)TOTAL_E;
    p = (char*)(((size_t)p + 255) & ~(size_t)255);
    short* WfA = (short*)p;    p += 16384 * 2;               // layer-1 W frags
    short* WfB = (short*)p;    p += 16384 * 2;               // layer-2 W frags
    p = (char*)(((size_t)p + 255) & ~(size_t)255);
    __half* bufL0h = (__half*)p;  p += (size_t)N_NODES * D * 2;
    __half* bufL1h = (__half*)p;  p += (size_t)N_NODES * D * 2;
    __half* h2h    = (__half*)p;  p += (size_t)N_NODES * D * 2;
    p = (char*)(((size_t)p + 255) & ~(size_t)255);
    float* bufH = (float*)p;   p += (size_t)N_NODES * D * 4;

    const int aggGrid  = (N_NODES + 31) / 32;
    const int scorGrid = (TOTAL_E / 2 * 8 + 255) / 256;

    // ---- W fragment prep (tiny) ----
    wprep_kernel<<<32, 256, 0, stream>>>(W1_0, W1_1, WfA);
    wprep_kernel<<<32, 256, 0, stream>>>(W2_0, W2_1, WfB);

    // ---- degrees + binning (no per-edge global atomics anywhere) ----
    countA_kernel<<<NCHUNK, 512, 0, stream>>>(s0, d0, s1, d1, hist);
    scan1_kernel<<<SCAN_NB2, SCAN_BS, 0, stream>>>(hist, OFS, bsum);
    scan2_kernel<<<1, 1024, 0, stream>>>(bsum);
    scan3_kernel<<<SCAN_NB2, SCAN_BS, 0, stream>>>(OFS, bsum);
    scatterA_kernel<<<NCHUNK, 512, 0, stream>>>(s0, d0, s1, d1, OFS, binned, binnedS);
    sortB_kernel<<<NBUCK, 512, 0, stream>>>(binned, OFS, ip0, ip1, c0a, c1a);
    countO_kernel<<<NBUCK, 512, 0, stream>>>(binnedS, OFS, cntO0, cntO1);

    // ---- layer 1 ----
    lin2m_kernel<<<L2M_GRID, 256, 0, stream>>>(x, WfA, cntO0, cntO1, bufL0h, bufL1h);
    aggC_kernel<1, 0><<<aggGrid, 256, 0, stream>>>(bufL0h, bufL1h, binned, ip0, ip1,
                                                   c0a, c1a, b1_0, b1_1, bufH, nullptr);

    // ---- layer 2 ----
    lin2m_kernel<<<L2M_GRID, 256, 0, stream>>>(bufH, WfB, cntO0, cntO1, bufL0h, bufL1h);
    aggC_kernel<0, 1><<<aggGrid, 256, 0, stream>>>(bufL0h, bufL1h, binned, ip0, ip1,
                                                   c0a, c1a, b2_0, b2_1, nullptr, h2h);

    // ---- scores ----
    score_kernel<<<scorGrid, 256, 0, stream>>>(h2h, s0, d0, nsrc, ndst, out);
}